// Round 5
// baseline (102.215 us; speedup 1.0000x reference)
//
#include <hip/hip_runtime.h>
#include <math.h>

static constexpr int CHUNK = 8;           // members per thread (seg path)
static constexpr int TPB   = 256;         // threads per block
static constexpr int MPB   = TPB * CHUNK; // 2048 members per seg block
static constexpr int LOCAL_BINS = 640;    // LDS bins cap (span/block ~43 typical)
static constexpr int ROWS_PER_BLOCK = 16; // mlp path: 4 waves x 4 rows

// ---------------------------------------------------------------------------
// Workspace zero (rocclr fillBufferAligned is slow for small fills).
// ---------------------------------------------------------------------------
__global__ __launch_bounds__(256)
void zero_ws_kernel(float4* __restrict__ ws, int n4) {
  int i = blockIdx.x * blockDim.x + threadIdx.x;
  int stride = gridDim.x * blockDim.x;
  for (; i < n4; i += stride) ws[i] = make_float4(0.f, 0.f, 0.f, 0.f);
}

// ---------------------------------------------------------------------------
// Fused kernel: seg-reduction blocks and MLP blocks Bresenham-interleaved so
// both HBM streams stay in flight concurrently.
//
// seg role: sorted segment reduction. Fast path: chunk entirely inside one
//   segment (prob ~ 1 - CHUNK/runlen ~ 83%) -> branchless sum + single flush.
//   Slow path: run-length scan. Interior segments -> plain store; edge
//   segments -> HW fp atomic.
// mlp role: 16 lanes per row, 4 rows per wave, 4-stage butterfly.
// ---------------------------------------------------------------------------
__global__ __launch_bounds__(TPB)
void fused_kernel(const float* __restrict__ lm,
                  const float* __restrict__ pos,
                  const int*   __restrict__ idx,
                  const float* __restrict__ gf,
                  const float* __restrict__ w,
                  const float* __restrict__ bptr,
                  const float* __restrict__ noise,
                  const int*   __restrict__ temp_ptr,
                  float* __restrict__ seg_sum,     // [G]
                  float* __restrict__ center_raw,  // [3G]
                  float* __restrict__ out,         // [5G]
                  int M, int G, int nseg, int ntot) {
  __shared__ float bins[LOCAL_BINS * 4];

  long long r = blockIdx.x;
  int segcum  = (int)((r * (long long)nseg) / ntot);
  int segcum1 = (int)(((r + 1) * (long long)nseg) / ntot);

  if (segcum1 != segcum) {
    // ---------------- seg role ----------------
    int blockBase = segcum * MPB;
    if (blockBase >= M) return;
    int blockEnd = min(blockBase + MPB, M);
    int g_first = idx[blockBase];
    int g_last  = idx[blockEnd - 1];
    int span    = g_last - g_first + 1;
    int nbins   = min(span, LOCAL_BINS);

    for (int i = threadIdx.x; i < nbins * 4; i += TPB) bins[i] = 0.f;
    __syncthreads();

    int base = blockBase + threadIdx.x * CHUNK;
    if (base < M) {
      auto flush = [&](int g, float se, float sx, float sy, float sz) {
        int off = g - g_first;
        if (off < LOCAL_BINS) {
          unsafeAtomicAdd(&bins[off*4+0], se);
          unsafeAtomicAdd(&bins[off*4+1], sx);
          unsafeAtomicAdd(&bins[off*4+2], sy);
          unsafeAtomicAdd(&bins[off*4+3], sz);
        } else {
          unsafeAtomicAdd(&seg_sum[g], se);
          unsafeAtomicAdd(&center_raw[3*g+0], sx);
          unsafeAtomicAdd(&center_raw[3*g+1], sy);
          unsafeAtomicAdd(&center_raw[3*g+2], sz);
        }
      };

      if (base + CHUNK <= M) {
        // full chunk: vector loads, no tail checks
        const int4*   i4 = (const int4*)(idx + base);
        const float4* l4 = (const float4*)(lm + base);
        const float4* p4 = (const float4*)(pos + (size_t)base * 3);
        int4 ia = i4[0], ic = i4[1];
        float4 la = l4[0], lc = l4[1];
        float4 pA = p4[0], pB = p4[1], pC = p4[2],
               pD = p4[3], pE = p4[4], pF = p4[5];
        int   ib[CHUNK] = {ia.x,ia.y,ia.z,ia.w, ic.x,ic.y,ic.z,ic.w};
        float eb[CHUNK];
        eb[0]=__expf(la.x); eb[1]=__expf(la.y); eb[2]=__expf(la.z); eb[3]=__expf(la.w);
        eb[4]=__expf(lc.x); eb[5]=__expf(lc.y); eb[6]=__expf(lc.z); eb[7]=__expf(lc.w);
        float pb[CHUNK*3] = {pA.x,pA.y,pA.z,pA.w, pB.x,pB.y,pB.z,pB.w,
                             pC.x,pC.y,pC.z,pC.w, pD.x,pD.y,pD.z,pD.w,
                             pE.x,pE.y,pE.z,pE.w, pF.x,pF.y,pF.z,pF.w};

        if (ib[0] == ib[CHUNK-1]) {
          // FAST PATH (~83%): entire chunk in one segment, branchless
          float se = 0.f, sx = 0.f, sy = 0.f, sz = 0.f;
          #pragma unroll
          for (int j = 0; j < CHUNK; j++) {
            se += eb[j];
            sx += pb[3*j+0] * eb[j];
            sy += pb[3*j+1] * eb[j];
            sz += pb[3*j+2] * eb[j];
          }
          flush(ib[0], se, sx, sy, sz);
        } else {
          // boundary chunk: run-length scan
          int cur = ib[0];
          float se = 0.f, sx = 0.f, sy = 0.f, sz = 0.f;
          #pragma unroll
          for (int j = 0; j < CHUNK; j++) {
            if (ib[j] != cur) {
              flush(cur, se, sx, sy, sz);
              cur = ib[j]; se = 0.f; sx = 0.f; sy = 0.f; sz = 0.f;
            }
            se += eb[j];
            sx += pb[3*j+0] * eb[j];
            sy += pb[3*j+1] * eb[j];
            sz += pb[3*j+2] * eb[j];
          }
          flush(cur, se, sx, sy, sz);
        }
      } else {
        // tail thread (last block only)
        int nj = M - base;
        int cur = idx[base];
        float se = 0.f, sx = 0.f, sy = 0.f, sz = 0.f;
        for (int j = 0; j < nj; j++) {
          int g = idx[base + j];
          float e = __expf(lm[base + j]);
          if (g != cur) {
            flush(cur, se, sx, sy, sz);
            cur = g; se = 0.f; sx = 0.f; sy = 0.f; sz = 0.f;
          }
          se += e;
          sx += pos[(size_t)(base+j)*3+0] * e;
          sy += pos[(size_t)(base+j)*3+1] * e;
          sz += pos[(size_t)(base+j)*3+2] * e;
        }
        flush(cur, se, sx, sy, sz);
      }
    }
    __syncthreads();

    for (int i = threadIdx.x; i < nbins; i += TPB) {
      int g = g_first + i;
      float s0 = bins[i*4+0], s1 = bins[i*4+1], s2 = bins[i*4+2], s3 = bins[i*4+3];
      if (g == g_first || g == g_last) {
        unsafeAtomicAdd(&seg_sum[g], s0);
        unsafeAtomicAdd(&center_raw[3*g+0], s1);
        unsafeAtomicAdd(&center_raw[3*g+1], s2);
        unsafeAtomicAdd(&center_raw[3*g+2], s3);
      } else {
        seg_sum[g] = s0;
        center_raw[3*g+0] = s1;
        center_raw[3*g+1] = s2;
        center_raw[3*g+2] = s3;
      }
    }
  } else {
    // ---------------- mlp role ----------------
    int mb   = (int)(r - segcum);
    int wid  = threadIdx.x >> 6;
    int lane = threadIdx.x & 63;
    int sub  = lane & 15;        // lane within 16-lane row group
    int rg   = lane >> 4;        // row group within wave
    int row  = (mb * 4 + wid) * 4 + rg;

    float d = 0.f;
    if (row < G) {
      const float4* grow = (const float4*)(gf + (size_t)row * 256);
      const float4* w4   = (const float4*)w;
      #pragma unroll
      for (int q = 0; q < 4; q++) {
        float4 gv = grow[sub + 16*q];
        float4 wv = w4[sub + 16*q];
        d += gv.x*wv.x + gv.y*wv.y + gv.z*wv.z + gv.w*wv.w;
      }
    }
    #pragma unroll
    for (int m = 8; m >= 1; m >>= 1) d += __shfl_xor(d, m, 64);

    if (sub == 0 && row < G) {
      float bb = bptr[0];
      int iv = temp_ptr[0];
      float t = (iv > -(1 << 23) && iv < (1 << 23)) ? (float)iv : __int_as_float(iv);
      float logit = 8.8f * tanhf(d + bb);
      float n = noise[row];
      float logistic = logf(n) - log1pf(-n);
      float x = (logit + logistic) / t;
      float lz = fminf(x, 0.f) - log1pf(expf(-fabsf(x)));
      out[row]     = lz;
      out[G + row] = logit;
    }
  }
}

// ---------------------------------------------------------------------------
// Center normalize: out[2G + i] = center_raw[i] / seg_sum[i/3] (0 if empty).
// ---------------------------------------------------------------------------
__global__ __launch_bounds__(256)
void norm_kernel(const float* __restrict__ seg_sum,
                 const float* __restrict__ center_raw,
                 float* __restrict__ out, int G) {
  int i = blockIdx.x * blockDim.x + threadIdx.x;
  int n = 3 * G;
  if (i < n) {
    int g = i / 3;
    float s = seg_sum[g];
    float inv = (s > 0.f) ? (1.f / s) : 0.f;
    out[(size_t)2 * G + i] = center_raw[i] * inv;
  }
}

extern "C" void kernel_launch(void* const* d_in, const int* in_sizes, int n_in,
                              void* d_out, int out_size, void* d_ws, size_t ws_size,
                              hipStream_t stream) {
  const float* gf    = (const float*)d_in[0];
  const float* pos   = (const float*)d_in[1];
  const float* lm    = (const float*)d_in[2];
  const int*   idx   = (const int*)  d_in[3];
  const float* w     = (const float*)d_in[4];
  const float* b     = (const float*)d_in[5];
  const float* noise = (const float*)d_in[6];
  const int*   temp  = (const int*)  d_in[7];
  float* out = (float*)d_out;

  int G = in_sizes[6];
  int M = in_sizes[3];

  float* seg_sum    = (float*)d_ws;
  float* center_raw = seg_sum + G;

  int n4 = (4 * G) / 4;
  hipLaunchKernelGGL(zero_ws_kernel, dim3(784), dim3(256), 0, stream,
                     (float4*)d_ws, n4);

  int nseg = (M + MPB - 1) / MPB;
  int nmlp = (G + ROWS_PER_BLOCK - 1) / ROWS_PER_BLOCK;
  int ntot = nseg + nmlp;
  hipLaunchKernelGGL(fused_kernel, dim3(ntot), dim3(TPB), 0, stream,
                     lm, pos, idx, gf, w, b, noise, temp,
                     seg_sum, center_raw, out, M, G, nseg, ntot);

  int nblk = (3 * G + 255) / 256;
  hipLaunchKernelGGL(norm_kernel, dim3(nblk), dim3(256), 0, stream,
                     seg_sum, center_raw, out, G);
}